// Round 6
// baseline (87.602 us; speedup 1.0000x reference)
//
#include <hip/hip_runtime.h>
#include <hip/hip_bf16.h>

// B=8, S=2048, D_MODEL=1024, D_K=D_V=64, causal, fp32 in/out.
// ws: Qb bf16[16384][64] | Kb bf16[16384][64] | Vt bf16[8][64][2048] | Wb bf16[192][1024]

typedef __attribute__((ext_vector_type(4))) float f32x4;
typedef __attribute__((ext_vector_type(8))) short short8;
typedef __attribute__((ext_vector_type(4))) short short4v;

#define MFMA16(a, b, c) __builtin_amdgcn_mfma_f32_16x16x32_bf16((a), (b), (c), 0, 0, 0)

__device__ __forceinline__ unsigned short f2bf(float f) {
    unsigned int u = __float_as_uint(f);
    unsigned int r = (u + 0x7FFFu + ((u >> 16) & 1u)) >> 16;
    return (unsigned short)r;
}
// HW packed fp32->bf16 RNE (gfx950)
__device__ __forceinline__ unsigned int cvtpk2(float lo, float hi) {
    unsigned int r;
    asm("v_cvt_pk_bf16_f32 %0, %1, %2" : "=v"(r) : "v"(lo), "v"(hi));
    return r;
}
__device__ __forceinline__ f32x4 zero4() {
    f32x4 z = {0.f, 0.f, 0.f, 0.f};
    return z;
}
__device__ __forceinline__ void async16(const unsigned short* gsrc, unsigned short* ldst) {
    __builtin_amdgcn_global_load_lds(
        (const __attribute__((address_space(1))) unsigned int*)gsrc,
        (__attribute__((address_space(3))) unsigned int*)ldst, 16, 0, 0);
}

// ---------------------------------------------------------------------------
// Kernel 0: W_Q|W_K|W_V fp32[64][1024] -> Wb bf16[192][1024]
// ---------------------------------------------------------------------------
__global__ __launch_bounds__(256) void wconv(
    const float* __restrict__ wq, const float* __restrict__ wk,
    const float* __restrict__ wv, unsigned short* __restrict__ Wb)
{
    const int idx = (blockIdx.x * 256 + threadIdx.x) * 8;
    const int r = idx >> 10, c = idx & 1023;
    const float* src = (r < 64)  ? (wq + (long)r * 1024 + c)
                     : (r < 128) ? (wk + (long)(r - 64) * 1024 + c)
                     :             (wv + (long)(r - 128) * 1024 + c);
    f32x4 v0 = *(const f32x4*)src;
    f32x4 v1 = *(const f32x4*)(src + 4);
    short8 o;
    ((unsigned int*)&o)[0] = cvtpk2(v0[0], v0[1]);
    ((unsigned int*)&o)[1] = cvtpk2(v0[2], v0[3]);
    ((unsigned int*)&o)[2] = cvtpk2(v1[0], v1[1]);
    ((unsigned int*)&o)[3] = cvtpk2(v1[2], v1[3]);
    *(short8*)(Wb + idx) = o;
}

// ---------------------------------------------------------------------------
// Kernel 1: QKV GEMM. BM=32, BN=192, BK=64, dbuf LDS, raw-barrier schedule:
// prefetch issued at top, vmcnt(0) drain AFTER compute (overlapped), one
// s_barrier per iter (A-tile handoff only; B slices are wave-private).
// ---------------------------------------------------------------------------
__global__ __launch_bounds__(256, 2) void qkv_gemm(
    const float* __restrict__ x,
    const unsigned short* __restrict__ Wb,
    unsigned short* __restrict__ Qb,
    unsigned short* __restrict__ Kb,
    unsigned short* __restrict__ Vt)
{
    __shared__ __align__(16) unsigned short Blds[2][192 * 64];
    __shared__ __align__(16) unsigned short Alds[2][32 * 64];

    const int tid  = threadIdx.x;
    const int lane = tid & 63;
    const int wid  = tid >> 6;
    const int c16  = lane & 15;
    const int g    = lane >> 4;
    const long m0  = (long)blockIdx.x * 32;

    const int o0    = wid * 6144 + lane * 16;
    const int brow0 = o0 >> 7;
    const int boff0 = o0 & 127;
    const unsigned short* bsrc0 =
        Wb + (long)brow0 * 1024 + ((boff0 ^ ((brow0 & 7) << 4)) >> 1);

    const int ar  = tid >> 3, acq = tid & 7;
    const float* asrc = x + (m0 + ar) * 1024 + acq * 8;
    const int aoff = ar * 64 + (((acq * 16) ^ ((ar & 7) << 4)) >> 1);

    f32x4 acc[2][3];
    #pragma unroll
    for (int i = 0; i < 2; ++i)
        #pragma unroll
        for (int j = 0; j < 3; ++j) acc[i][j] = zero4();

    // ---- prologue: stage chunk 0 ----
    {
        f32x4 a0 = *(const f32x4*)asrc;
        f32x4 a1 = *(const f32x4*)(asrc + 4);
        #pragma unroll
        for (int i = 0; i < 6; ++i)
            async16(bsrc0 + i * 8192, &Blds[0][wid * 3072 + i * 512]);
        short8 p;
        ((unsigned int*)&p)[0] = cvtpk2(a0[0], a0[1]);
        ((unsigned int*)&p)[1] = cvtpk2(a0[2], a0[3]);
        ((unsigned int*)&p)[2] = cvtpk2(a1[0], a1[1]);
        ((unsigned int*)&p)[3] = cvtpk2(a1[2], a1[3]);
        *(short8*)&Alds[0][aoff] = p;
        asm volatile("s_waitcnt vmcnt(0)" ::: "memory");
        asm volatile("s_waitcnt lgkmcnt(0)" ::: "memory");
        __builtin_amdgcn_s_barrier();
    }

    for (int it = 0; it < 16; ++it) {
        const int cur = it & 1, nxt = cur ^ 1;
        f32x4 a0, a1;
        if (it < 15) {
            const int k = (it + 1) * 64;
            a0 = *(const f32x4*)(asrc + k);
            a1 = *(const f32x4*)(asrc + k + 4);
            #pragma unroll
            for (int i = 0; i < 6; ++i)
                async16(bsrc0 + k + i * 8192, &Blds[nxt][wid * 3072 + i * 512]);
        }
        // ---- compute on cur ----
        #pragma unroll
        for (int kc = 0; kc < 2; ++kc) {
            const int q = kc * 64 + g * 16;
            short8 af[2], bf[3];
            #pragma unroll
            for (int mt = 0; mt < 2; ++mt) {
                const int rm = mt * 16 + c16;
                af[mt] = *(const short8*)&Alds[cur][rm * 64 + ((q ^ ((rm & 7) << 4)) >> 1)];
            }
            #pragma unroll
            for (int nt = 0; nt < 3; ++nt) {
                const int rb = wid * 48 + nt * 16 + c16;
                bf[nt] = *(const short8*)&Blds[cur][rb * 64 + ((q ^ ((rb & 7) << 4)) >> 1)];
            }
            #pragma unroll
            for (int mt = 0; mt < 2; ++mt)
                #pragma unroll
                for (int nt = 0; nt < 3; ++nt)
                    acc[mt][nt] = MFMA16(af[mt], bf[nt], acc[mt][nt]);
        }
        if (it < 15) {
            short8 p;
            ((unsigned int*)&p)[0] = cvtpk2(a0[0], a0[1]);
            ((unsigned int*)&p)[1] = cvtpk2(a0[2], a0[3]);
            ((unsigned int*)&p)[2] = cvtpk2(a1[0], a1[1]);
            ((unsigned int*)&p)[3] = cvtpk2(a1[2], a1[3]);
            asm volatile("s_waitcnt vmcnt(0)" ::: "memory");   // B(nxt) landed; after compute
            *(short8*)&Alds[nxt][aoff] = p;
            asm volatile("s_waitcnt lgkmcnt(0)" ::: "memory"); // A write + own reads done
            __builtin_amdgcn_s_barrier();                       // A-tile handoff
        }
    }

    // ---- epilogue: D layout col=c16, row=g*4+r ----
    const long bb = m0 >> 11;
    #pragma unroll
    for (int mt = 0; mt < 2; ++mt) {
        const long mrow = m0 + mt * 16 + g * 4;
        const long ss = mrow & 2047;
        #pragma unroll
        for (int nt = 0; nt < 3; ++nt) {
            const int n = wid * 48 + nt * 16 + c16;
            if (n < 64) {
                #pragma unroll
                for (int r = 0; r < 4; ++r)
                    Qb[(mrow + r) * 64 + n] = f2bf(acc[mt][nt][r]);
            } else if (n < 128) {
                #pragma unroll
                for (int r = 0; r < 4; ++r)
                    Kb[(mrow + r) * 64 + (n - 64)] = f2bf(acc[mt][nt][r]);
            } else {
                short4v pv = { (short)f2bf(acc[mt][nt][0]), (short)f2bf(acc[mt][nt][1]),
                               (short)f2bf(acc[mt][nt][2]), (short)f2bf(acc[mt][nt][3]) };
                *(short4v*)&Vt[((bb * 64) + (n - 128)) * 2048 + ss] = pv;
            }
        }
    }
}

// ---------------------------------------------------------------------------
// Kernel 2: causal attention, swapped-QK^T (S^T = mfma(K,Q)) so each lane
// owns one q-row (q=c16); P packs in-register via cvt_pk into the PV
// A-fragment. ZERO LDS / shuffles / scalar stores in the kv loop.
// Block = 256 thr (4 waves), 16 q-rows; waves split KV 4-ways; plain-sum
// merge (no max tracking: |s/8| < ~5, exp safe, softmax scale-free).
// PV slot map: A slot k=8g+j  <->  kv = kv0 + (j>>2)*16 + 4g + (j&3).
// ---------------------------------------------------------------------------
__global__ __launch_bounds__(256, 4) void attn_fwd(
    const unsigned short* __restrict__ Qb,
    const unsigned short* __restrict__ Kb,
    const unsigned short* __restrict__ Vt,
    float* __restrict__ out)
{
    __shared__ __align__(16) float Obuf[64 * 64];   // [wid*16+q][v] 16KB
    __shared__ float lbuf[64];                      // [wid*16+q]

    const int tid  = threadIdx.x;
    const int lane = tid & 63;
    const int wid  = tid >> 6;
    const int c16  = lane & 15;
    const int g    = lane >> 4;
    const int bidx = blockIdx.x;
    const int b    = bidx & 7;              // batch -> XCD (L2 locality)
    const int qt   = 127 - (bidx >> 3);     // longest first
    const int q0   = qt * 16;

    // Q fragments (B-operand: row q = q0+c16)
    const unsigned short* qrow = Qb + ((long)b * 2048 + q0 + c16) * 64;
    const short8 qf0 = *(const short8*)(qrow + g * 8);
    const short8 qf1 = *(const short8*)(qrow + 32 + g * 8);
    const unsigned short* Kbase = Kb + (long)b * 2048 * 64;
    const unsigned short* Vbase = Vt + (long)b * 64 * 2048;

    f32x4 acc[4];
    #pragma unroll
    for (int vt = 0; vt < 4; ++vt) acc[vt] = zero4();
    float lp = 0.f;

    const float SCL = 0.18033688f;   // log2(e)/8
    const int qg   = q0 + c16;       // this lane's q row
    const int n_kv = q0 + 16;
    const int nb   = (n_kv + 31) >> 5;
    const int cl   = (nb + 3) >> 2;
    const int blo  = min(wid * cl, nb);
    const int bhi  = min(blo + cl, nb);

    for (int blk = blo; blk < bhi; ++blk) {
        const int kv0 = blk * 32;
        // V fragments: slots j=0..3 <- kv0+4g+j, j=4..7 <- kv0+16+4g+j
        short8 vf[4];
        #pragma unroll
        for (int vt = 0; vt < 4; ++vt) {
            const unsigned short* vrow = Vbase + (long)(vt * 16 + c16) * 2048 + kv0 + 4 * g;
            ((short4v*)&vf[vt])[0] = *(const short4v*)vrow;
            ((short4v*)&vf[vt])[1] = *(const short4v*)(vrow + 16);
        }
        // S^T = mfma(K, Q): lane holds S[kv0+nt*16+4g+r][q=c16]
        f32x4 s[2];
        #pragma unroll
        for (int nt = 0; nt < 2; ++nt) {
            const unsigned short* krow = Kbase + (long)(kv0 + nt * 16 + c16) * 64;
            short8 kf0 = *(const short8*)(krow + g * 8);
            short8 kf1 = *(const short8*)(krow + 32 + g * 8);
            f32x4 z = zero4();
            z = MFMA16(kf0, qf0, z);
            z = MFMA16(kf1, qf1, z);
            s[nt] = z;
        }
        // p = exp(s/8) with causal mask; pack A-fragment in-register
        short8 af;
        #pragma unroll
        for (int nt = 0; nt < 2; ++nt) {
            float p[4];
            #pragma unroll
            for (int r = 0; r < 4; ++r) {
                float v = exp2f(s[nt][r] * SCL);
                const int kvg = kv0 + nt * 16 + g * 4 + r;
                v = (kvg > qg) ? 0.f : v;
                lp += v;
                p[r] = v;
            }
            ((unsigned int*)&af)[nt * 2]     = cvtpk2(p[0], p[1]);
            ((unsigned int*)&af)[nt * 2 + 1] = cvtpk2(p[2], p[3]);
        }
        // PV: one 16x16x32 mfma per vt covers all 32 kv
        #pragma unroll
        for (int vt = 0; vt < 4; ++vt)
            acc[vt] = MFMA16(af, vf[vt], acc[vt]);
    }

    // l: reduce across the 4 g-groups holding q=c16
    lp += __shfl_xor(lp, 16);
    lp += __shfl_xor(lp, 32);

    if (g == 0) lbuf[wid * 16 + c16] = lp;
    #pragma unroll
    for (int vt = 0; vt < 4; ++vt)
        #pragma unroll
        for (int r = 0; r < 4; ++r)
            Obuf[(wid * 16 + g * 4 + r) * 64 + vt * 16 + c16] = acc[vt][r];
    __syncthreads();

    // merge 4 KV-split partials: plain sums
    const int row = tid >> 4;
    const int c0  = (tid & 15) * 4;
    float l = 0.f;
    #pragma unroll
    for (int w = 0; w < 4; ++w) l += lbuf[w * 16 + row];
    const float inv = 1.0f / l;
    f32x4 o = zero4();
    #pragma unroll
    for (int w = 0; w < 4; ++w) {
        const float* Orow = Obuf + (w * 16 + row) * 64 + c0;
        f32x4 t = *(const f32x4*)Orow;
        #pragma unroll
        for (int j = 0; j < 4; ++j) o[j] += t[j];
    }
    #pragma unroll
    for (int j = 0; j < 4; ++j) o[j] *= inv;
    *(f32x4*)(out + ((long)b * 2048 + q0 + row) * 64 + c0) = o;
}

extern "C" void kernel_launch(void* const* d_in, const int* in_sizes, int n_in,
                              void* d_out, int out_size, void* d_ws, size_t ws_size,
                              hipStream_t stream)
{
    const float* x  = (const float*)d_in[0];
    const float* wq = (const float*)d_in[1];
    const float* wk = (const float*)d_in[2];
    const float* wv = (const float*)d_in[3];

    unsigned short* Qb = (unsigned short*)d_ws;
    unsigned short* Kb = Qb + (size_t)16384 * 64;
    unsigned short* Vt = Kb + (size_t)16384 * 64;
    unsigned short* Wb = Vt + (size_t)8 * 64 * 2048;
    float* out = (float*)d_out;

    wconv<<<dim3(96), dim3(256), 0, stream>>>(wq, wk, wv, Wb);
    qkv_gemm<<<dim3(512), dim3(256), 0, stream>>>(x, Wb, Qb, Kb, Vt);
    attn_fwd<<<dim3(1024), dim3(256), 0, stream>>>(Qb, Kb, Vt, out);
}

// Round 7
// 75.226 us; speedup vs baseline: 1.1645x; 1.1645x over previous
//
#include <hip/hip_runtime.h>
#include <hip/hip_bf16.h>

// B=8, S=2048, D_MODEL=1024, D_K=D_V=64, causal, fp32 in/out.
// ws: Qb bf16[16384][64] | Kb bf16[16384][64] | Vt bf16[8][64][2048] | Wb bf16[192][1024]

typedef __attribute__((ext_vector_type(4))) float f32x4;
typedef __attribute__((ext_vector_type(8))) short short8;
typedef __attribute__((ext_vector_type(4))) short short4v;

#define MFMA16(a, b, c) __builtin_amdgcn_mfma_f32_16x16x32_bf16((a), (b), (c), 0, 0, 0)

__device__ __forceinline__ unsigned short f2bf(float f) {
    unsigned int u = __float_as_uint(f);
    unsigned int r = (u + 0x7FFFu + ((u >> 16) & 1u)) >> 16;
    return (unsigned short)r;
}
// HW packed fp32->bf16 RNE (gfx950)
__device__ __forceinline__ unsigned int cvtpk2(float lo, float hi) {
    unsigned int r;
    asm("v_cvt_pk_bf16_f32 %0, %1, %2" : "=v"(r) : "v"(lo), "v"(hi));
    return r;
}
__device__ __forceinline__ f32x4 zero4() {
    f32x4 z = {0.f, 0.f, 0.f, 0.f};
    return z;
}
__device__ __forceinline__ void async16(const unsigned short* gsrc, unsigned short* ldst) {
    __builtin_amdgcn_global_load_lds(
        (const __attribute__((address_space(1))) unsigned int*)gsrc,
        (__attribute__((address_space(3))) unsigned int*)ldst, 16, 0, 0);
}

// ---------------------------------------------------------------------------
// Kernel 0: W_Q|W_K|W_V fp32[64][1024] -> Wb bf16[192][1024]
// ---------------------------------------------------------------------------
__global__ __launch_bounds__(256) void wconv(
    const float* __restrict__ wq, const float* __restrict__ wk,
    const float* __restrict__ wv, unsigned short* __restrict__ Wb)
{
    const int idx = (blockIdx.x * 256 + threadIdx.x) * 8;
    const int r = idx >> 10, c = idx & 1023;
    const float* src = (r < 64)  ? (wq + (long)r * 1024 + c)
                     : (r < 128) ? (wk + (long)(r - 64) * 1024 + c)
                     :             (wv + (long)(r - 128) * 1024 + c);
    f32x4 v0 = *(const f32x4*)src;
    f32x4 v1 = *(const f32x4*)(src + 4);
    short8 o;
    ((unsigned int*)&o)[0] = cvtpk2(v0[0], v0[1]);
    ((unsigned int*)&o)[1] = cvtpk2(v0[2], v0[3]);
    ((unsigned int*)&o)[2] = cvtpk2(v1[0], v1[1]);
    ((unsigned int*)&o)[3] = cvtpk2(v1[2], v1[3]);
    *(short8*)(Wb + idx) = o;
}

// ---------------------------------------------------------------------------
// Kernel 1: QKV GEMM. BM=32, BN=192, BK=64, dbuf LDS.
// A (x, HBM stream): register prefetch DEPTH 2 + counted vmcnt(2) so the
// barrier drain waits only the B asyncs; A(it+2) stays in flight (~2 iters
// to cover ~900cy HBM latency). B slices are wave-private (rows 48w..48w+47).
// ---------------------------------------------------------------------------
__global__ __launch_bounds__(256, 2) void qkv_gemm(
    const float* __restrict__ x,
    const unsigned short* __restrict__ Wb,
    unsigned short* __restrict__ Qb,
    unsigned short* __restrict__ Kb,
    unsigned short* __restrict__ Vt)
{
    __shared__ __align__(16) unsigned short Blds[2][192 * 64];
    __shared__ __align__(16) unsigned short Alds[2][32 * 64];

    const int tid  = threadIdx.x;
    const int lane = tid & 63;
    const int wid  = tid >> 6;
    const int c16  = lane & 15;
    const int g    = lane >> 4;
    const long m0  = (long)blockIdx.x * 32;

    const int o0    = wid * 6144 + lane * 16;
    const int brow0 = o0 >> 7;
    const int boff0 = o0 & 127;
    const unsigned short* bsrc0 =
        Wb + (long)brow0 * 1024 + ((boff0 ^ ((brow0 & 7) << 4)) >> 1);

    const int ar  = tid >> 3, acq = tid & 7;
    const float* asrc = x + (m0 + ar) * 1024 + acq * 8;
    const int aoff = ar * 64 + (((acq * 16) ^ ((ar & 7) << 4)) >> 1);

    f32x4 acc[2][3];
    #pragma unroll
    for (int i = 0; i < 2; ++i)
        #pragma unroll
        for (int j = 0; j < 3; ++j) acc[i][j] = zero4();

    // ---- prologue: A(0)->LDS0, B(0) asyncs, A(1) in regs ----
    f32x4 na0, na1;
    {
        f32x4 pa0 = *(const f32x4*)asrc;
        f32x4 pa1 = *(const f32x4*)(asrc + 4);
        #pragma unroll
        for (int i = 0; i < 6; ++i)
            async16(bsrc0 + i * 8192, &Blds[0][wid * 3072 + i * 512]);
        na0 = *(const f32x4*)(asrc + 64);
        na1 = *(const f32x4*)(asrc + 68);
        short8 p;
        ((unsigned int*)&p)[0] = cvtpk2(pa0[0], pa0[1]);
        ((unsigned int*)&p)[1] = cvtpk2(pa0[2], pa0[3]);
        ((unsigned int*)&p)[2] = cvtpk2(pa1[0], pa1[1]);
        ((unsigned int*)&p)[3] = cvtpk2(pa1[2], pa1[3]);
        *(short8*)&Alds[0][aoff] = p;
        asm volatile("s_waitcnt vmcnt(2)" ::: "memory");   // B(0) done; A(1) flying
        asm volatile("s_waitcnt lgkmcnt(0)" ::: "memory");
        __builtin_amdgcn_s_barrier();
    }

    #pragma unroll 2
    for (int it = 0; it < 16; ++it) {
        const int cur = it & 1, nxt = cur ^ 1;
        if (it < 15) {
            const int k = (it + 1) * 64;
            #pragma unroll
            for (int i = 0; i < 6; ++i)
                async16(bsrc0 + k + i * 8192, &Blds[nxt][wid * 3072 + i * 512]);
        }
        f32x4 qa0, qa1;
        if (it < 14) {
            const int k2 = (it + 2) * 64;
            qa0 = *(const f32x4*)(asrc + k2);
            qa1 = *(const f32x4*)(asrc + k2 + 4);
        }
        // ---- compute on cur ----
        #pragma unroll
        for (int kc = 0; kc < 2; ++kc) {
            const int q = kc * 64 + g * 16;
            short8 af[2], bf[3];
            #pragma unroll
            for (int mt = 0; mt < 2; ++mt) {
                const int rm = mt * 16 + c16;
                af[mt] = *(const short8*)&Alds[cur][rm * 64 + ((q ^ ((rm & 7) << 4)) >> 1)];
            }
            #pragma unroll
            for (int nt = 0; nt < 3; ++nt) {
                const int rb = wid * 48 + nt * 16 + c16;
                bf[nt] = *(const short8*)&Blds[cur][rb * 64 + ((q ^ ((rb & 7) << 4)) >> 1)];
            }
            #pragma unroll
            for (int mt = 0; mt < 2; ++mt)
                #pragma unroll
                for (int nt = 0; nt < 3; ++nt)
                    acc[mt][nt] = MFMA16(af[mt], bf[nt], acc[mt][nt]);
        }
        if (it < 15) {
            short8 p;
            ((unsigned int*)&p)[0] = cvtpk2(na0[0], na0[1]);
            ((unsigned int*)&p)[1] = cvtpk2(na0[2], na0[3]);
            ((unsigned int*)&p)[2] = cvtpk2(na1[0], na1[1]);
            ((unsigned int*)&p)[3] = cvtpk2(na1[2], na1[3]);
            if (it < 14) {
                asm volatile("s_waitcnt vmcnt(2)" ::: "memory");  // B(nxt) done; A(it+2) flying
            } else {
                asm volatile("s_waitcnt vmcnt(0)" ::: "memory");
            }
            *(short8*)&Alds[nxt][aoff] = p;
            asm volatile("s_waitcnt lgkmcnt(0)" ::: "memory");
            __builtin_amdgcn_s_barrier();
            na0 = qa0; na1 = qa1;
        }
    }

    // ---- epilogue: D layout col=c16, row=g*4+r ----
    const long bb = m0 >> 11;
    #pragma unroll
    for (int mt = 0; mt < 2; ++mt) {
        const long mrow = m0 + mt * 16 + g * 4;
        const long ss = mrow & 2047;
        #pragma unroll
        for (int nt = 0; nt < 3; ++nt) {
            const int n = wid * 48 + nt * 16 + c16;
            if (n < 64) {
                #pragma unroll
                for (int r = 0; r < 4; ++r)
                    Qb[(mrow + r) * 64 + n] = f2bf(acc[mt][nt][r]);
            } else if (n < 128) {
                #pragma unroll
                for (int r = 0; r < 4; ++r)
                    Kb[(mrow + r) * 64 + (n - 64)] = f2bf(acc[mt][nt][r]);
            } else {
                short4v pv = { (short)f2bf(acc[mt][nt][0]), (short)f2bf(acc[mt][nt][1]),
                               (short)f2bf(acc[mt][nt][2]), (short)f2bf(acc[mt][nt][3]) };
                *(short4v*)&Vt[((bb * 64) + (n - 128)) * 2048 + ss] = pv;
            }
        }
    }
}

// ---------------------------------------------------------------------------
// Kernel 2: causal attention, swapped-QK^T, in-register P, no max tracking.
// Block = 512 thr (8 waves) handles the causal PAIR {tA=pr, tB=127-pr}
// (constant cost: nbA+nbB = 65 kv32-blocks). Waves are split between the two
// tiles proportionally to cost (wA = round(8*nbA/65)) -> every wave ~8-10
// kv-steps, no stragglers. Depth-1 register prefetch (ping-pong sets) hides
// L2 load latency under compute. Per-tile merge in LDS.
// PV slot map: A slot k=8g+j  <->  kv = kv0 + (j>>2)*16 + 4g + (j&3).
// ---------------------------------------------------------------------------
__global__ __launch_bounds__(512, 4) void attn_fwd(
    const unsigned short* __restrict__ Qb,
    const unsigned short* __restrict__ Kb,
    const unsigned short* __restrict__ Vt,
    float* __restrict__ out)
{
    __shared__ __align__(16) float Obuf[8 * 16 * 64];   // 32KB: [wave][row][col]
    __shared__ float lbuf[8 * 16];

    const int tid  = threadIdx.x;
    const int lane = tid & 63;
    const int wid  = tid >> 6;          // 0..7
    const int c16  = lane & 15;
    const int g    = lane >> 4;
    const int bidx = blockIdx.x;
    const int b    = bidx & 7;          // batch -> XCD (L2 locality)
    const int pr   = bidx >> 3;         // 0..63
    const int tA   = pr;
    const int tB   = 127 - pr;

    const int nbA = (16 * tA + 47) >> 5;   // kv32-blocks for tile A
    const int nbB = (16 * tB + 47) >> 5;   // nbA + nbB == 65
    int wA = (8 * nbA + 32) / 65;
    wA = max(1, min(7, wA));

    // wave -> (tile, split)
    int q0, nb, nw, wi;
    if (wid < wA) { q0 = tA * 16; nb = nbA; nw = wA;     wi = wid; }
    else          { q0 = tB * 16; nb = nbB; nw = 8 - wA; wi = wid - wA; }
    const int cl  = (nb + nw - 1) / nw;
    const int blo = min(wi * cl, nb);
    const int bhi = min(blo + cl, nb);

    // Q fragments (B-operand: q-row = q0 + c16)
    const unsigned short* qrow = Qb + ((long)b * 2048 + q0 + c16) * 64;
    const short8 qf0 = *(const short8*)(qrow + g * 8);
    const short8 qf1 = *(const short8*)(qrow + 32 + g * 8);
    const unsigned short* Kbase = Kb + (long)b * 2048 * 64;
    const unsigned short* Vbase = Vt + (long)b * 64 * 2048;

    f32x4 acc[4];
    #pragma unroll
    for (int vt = 0; vt < 4; ++vt) acc[vt] = zero4();
    float lp = 0.f;

    const float SCL = 0.18033688f;   // log2(e)/8
    const int qg = q0 + c16;

    short8 vfA[4], vfB[4];
    short8 kfA[2][2], kfB[2][2];

#define STEP_LOAD(KV0, VF, KF) do {                                            \
    const int _kv0 = (KV0);                                                    \
    _Pragma("unroll")                                                          \
    for (int vt = 0; vt < 4; ++vt) {                                           \
        const unsigned short* vrow =                                           \
            Vbase + (long)(vt * 16 + c16) * 2048 + _kv0 + 4 * g;               \
        ((short4v*)&VF[vt])[0] = *(const short4v*)vrow;                        \
        ((short4v*)&VF[vt])[1] = *(const short4v*)(vrow + 16);                 \
    }                                                                          \
    _Pragma("unroll")                                                          \
    for (int nt = 0; nt < 2; ++nt) {                                           \
        const unsigned short* krow =                                           \
            Kbase + (long)(_kv0 + nt * 16 + c16) * 64;                         \
        KF[nt][0] = *(const short8*)(krow + g * 8);                            \
        KF[nt][1] = *(const short8*)(krow + 32 + g * 8);                       \
    }                                                                          \
} while (0)

#define STEP_COMPUTE(KV0, VF, KF) do {                                         \
    const int _kv0 = (KV0);                                                    \
    f32x4 s[2];                                                                \
    _Pragma("unroll")                                                          \
    for (int nt = 0; nt < 2; ++nt) {                                           \
        f32x4 z = zero4();                                                     \
        z = MFMA16(KF[nt][0], qf0, z);                                         \
        z = MFMA16(KF[nt][1], qf1, z);                                         \
        s[nt] = z;                                                             \
    }                                                                          \
    short8 af;                                                                 \
    _Pragma("unroll")                                                          \
    for (int nt = 0; nt < 2; ++nt) {                                           \
        float p[4];                                                            \
        _Pragma("unroll")                                                      \
        for (int r = 0; r < 4; ++r) {                                          \
            float v = exp2f(s[nt][r] * SCL);                                   \
            const int kvg = _kv0 + nt * 16 + g * 4 + r;                        \
            v = (kvg > qg) ? 0.f : v;                                          \
            lp += v;                                                           \
            p[r] = v;                                                          \
        }                                                                      \
        ((unsigned int*)&af)[nt * 2]     = cvtpk2(p[0], p[1]);                 \
        ((unsigned int*)&af)[nt * 2 + 1] = cvtpk2(p[2], p[3]);                 \
    }                                                                          \
    _Pragma("unroll")                                                          \
    for (int vt = 0; vt < 4; ++vt)                                             \
        acc[vt] = MFMA16(af, VF[vt], acc[vt]);                                 \
} while (0)

    int blk = blo;
    if (blk < bhi) STEP_LOAD(blk * 32, vfA, kfA);
    while (blk < bhi) {
        if (blk + 1 < bhi) STEP_LOAD((blk + 1) * 32, vfB, kfB);
        STEP_COMPUTE(blk * 32, vfA, kfA);
        ++blk;
        if (blk >= bhi) break;
        if (blk + 1 < bhi) STEP_LOAD((blk + 1) * 32, vfA, kfA);
        STEP_COMPUTE(blk * 32, vfB, kfB);
        ++blk;
    }
#undef STEP_LOAD
#undef STEP_COMPUTE

    // l: reduce over the 4 g-groups holding q=c16
    lp += __shfl_xor(lp, 16);
    lp += __shfl_xor(lp, 32);
    if (g == 0) lbuf[wid * 16 + c16] = lp;

    #pragma unroll
    for (int vt = 0; vt < 4; ++vt)
        #pragma unroll
        for (int r = 0; r < 4; ++r)
            Obuf[(wid * 16 + g * 4 + r) * 64 + vt * 16 + c16] = acc[vt][r];
    __syncthreads();

    // merge: 512 items = 2 tiles x 16 rows x 16 col4-chunks
    const int tt  = tid >> 8;
    const int row = (tid >> 4) & 15;
    const int c0  = (tid & 15) * 4;
    const int wlo = tt ? wA : 0;
    const int whi = tt ? 8  : wA;
    const int q0o = (tt ? tB : tA) * 16;

    float l = 0.f;
    for (int w = wlo; w < whi; ++w) l += lbuf[w * 16 + row];
    const float inv = 1.0f / l;
    f32x4 o = zero4();
    for (int w = wlo; w < whi; ++w) {
        f32x4 t = *(const f32x4*)(Obuf + (w * 16 + row) * 64 + c0);
        #pragma unroll
        for (int j = 0; j < 4; ++j) o[j] += t[j];
    }
    #pragma unroll
    for (int j = 0; j < 4; ++j) o[j] *= inv;
    *(f32x4*)(out + ((long)b * 2048 + q0o + row) * 64 + c0) = o;
}

extern "C" void kernel_launch(void* const* d_in, const int* in_sizes, int n_in,
                              void* d_out, int out_size, void* d_ws, size_t ws_size,
                              hipStream_t stream)
{
    const float* x  = (const float*)d_in[0];
    const float* wq = (const float*)d_in[1];
    const float* wk = (const float*)d_in[2];
    const float* wv = (const float*)d_in[3];

    unsigned short* Qb = (unsigned short*)d_ws;
    unsigned short* Kb = Qb + (size_t)16384 * 64;
    unsigned short* Vt = Kb + (size_t)16384 * 64;
    unsigned short* Wb = Vt + (size_t)8 * 64 * 2048;
    float* out = (float*)d_out;

    wconv<<<dim3(96), dim3(256), 0, stream>>>(wq, wk, wv, Wb);
    qkv_gemm<<<dim3(512), dim3(256), 0, stream>>>(x, Wb, Qb, Kb, Vt);
    attn_fwd<<<dim3(512), dim3(512), 0, stream>>>(Qb, Kb, Vt, out);
}

// Round 8
// 56.731 us; speedup vs baseline: 1.5442x; 1.3260x over previous
//
#include <hip/hip_runtime.h>
#include <hip/hip_bf16.h>

// B=8, S=2048, D_MODEL=1024, D_K=D_V=64, causal, fp32 in/out.
// ws: Qb bf16[16384][64] | Kb bf16[16384][64] | Vt bf16[8][64][2048] | Wb bf16[192][1024]

typedef __attribute__((ext_vector_type(4))) float f32x4;
typedef __attribute__((ext_vector_type(8))) short short8;
typedef __attribute__((ext_vector_type(4))) short short4v;

#define MFMA16(a, b, c) __builtin_amdgcn_mfma_f32_16x16x32_bf16((a), (b), (c), 0, 0, 0)

__device__ __forceinline__ unsigned short f2bf(float f) {
    unsigned int u = __float_as_uint(f);
    unsigned int r = (u + 0x7FFFu + ((u >> 16) & 1u)) >> 16;
    return (unsigned short)r;
}
// HW packed fp32->bf16 RNE (gfx950)
__device__ __forceinline__ unsigned int cvtpk2(float lo, float hi) {
    unsigned int r;
    asm("v_cvt_pk_bf16_f32 %0, %1, %2" : "=v"(r) : "v"(lo), "v"(hi));
    return r;
}
__device__ __forceinline__ f32x4 zero4() {
    f32x4 z = {0.f, 0.f, 0.f, 0.f};
    return z;
}
__device__ __forceinline__ void async16(const unsigned short* gsrc, unsigned short* ldst) {
    __builtin_amdgcn_global_load_lds(
        (const __attribute__((address_space(1))) unsigned int*)gsrc,
        (__attribute__((address_space(3))) unsigned int*)ldst, 16, 0, 0);
}

// ---------------------------------------------------------------------------
// Kernel 0: W_Q|W_K|W_V fp32[64][1024] -> Wb bf16[192][1024]
// ---------------------------------------------------------------------------
__global__ __launch_bounds__(256) void wconv(
    const float* __restrict__ wq, const float* __restrict__ wk,
    const float* __restrict__ wv, unsigned short* __restrict__ Wb)
{
    const int idx = (blockIdx.x * 256 + threadIdx.x) * 8;
    const int r = idx >> 10, c = idx & 1023;
    const float* src = (r < 64)  ? (wq + (long)r * 1024 + c)
                     : (r < 128) ? (wk + (long)(r - 64) * 1024 + c)
                     :             (wv + (long)(r - 128) * 1024 + c);
    f32x4 v0 = *(const f32x4*)src;
    f32x4 v1 = *(const f32x4*)(src + 4);
    short8 o;
    ((unsigned int*)&o)[0] = cvtpk2(v0[0], v0[1]);
    ((unsigned int*)&o)[1] = cvtpk2(v0[2], v0[3]);
    ((unsigned int*)&o)[2] = cvtpk2(v1[0], v1[1]);
    ((unsigned int*)&o)[3] = cvtpk2(v1[2], v1[3]);
    *(short8*)(Wb + idx) = o;
}

// ---------------------------------------------------------------------------
// Kernel 1: QKV GEMM (unchanged from round 7). BM=32, BN=192, BK=64, dbuf LDS,
// A depth-2 register prefetch + counted vmcnt(2), B via global_load_lds.
// ---------------------------------------------------------------------------
__global__ __launch_bounds__(256, 2) void qkv_gemm(
    const float* __restrict__ x,
    const unsigned short* __restrict__ Wb,
    unsigned short* __restrict__ Qb,
    unsigned short* __restrict__ Kb,
    unsigned short* __restrict__ Vt)
{
    __shared__ __align__(16) unsigned short Blds[2][192 * 64];
    __shared__ __align__(16) unsigned short Alds[2][32 * 64];

    const int tid  = threadIdx.x;
    const int lane = tid & 63;
    const int wid  = tid >> 6;
    const int c16  = lane & 15;
    const int g    = lane >> 4;
    const long m0  = (long)blockIdx.x * 32;

    const int o0    = wid * 6144 + lane * 16;
    const int brow0 = o0 >> 7;
    const int boff0 = o0 & 127;
    const unsigned short* bsrc0 =
        Wb + (long)brow0 * 1024 + ((boff0 ^ ((brow0 & 7) << 4)) >> 1);

    const int ar  = tid >> 3, acq = tid & 7;
    const float* asrc = x + (m0 + ar) * 1024 + acq * 8;
    const int aoff = ar * 64 + (((acq * 16) ^ ((ar & 7) << 4)) >> 1);

    f32x4 acc[2][3];
    #pragma unroll
    for (int i = 0; i < 2; ++i)
        #pragma unroll
        for (int j = 0; j < 3; ++j) acc[i][j] = zero4();

    f32x4 na0, na1;
    {
        f32x4 pa0 = *(const f32x4*)asrc;
        f32x4 pa1 = *(const f32x4*)(asrc + 4);
        #pragma unroll
        for (int i = 0; i < 6; ++i)
            async16(bsrc0 + i * 8192, &Blds[0][wid * 3072 + i * 512]);
        na0 = *(const f32x4*)(asrc + 64);
        na1 = *(const f32x4*)(asrc + 68);
        short8 p;
        ((unsigned int*)&p)[0] = cvtpk2(pa0[0], pa0[1]);
        ((unsigned int*)&p)[1] = cvtpk2(pa0[2], pa0[3]);
        ((unsigned int*)&p)[2] = cvtpk2(pa1[0], pa1[1]);
        ((unsigned int*)&p)[3] = cvtpk2(pa1[2], pa1[3]);
        *(short8*)&Alds[0][aoff] = p;
        asm volatile("s_waitcnt vmcnt(2)" ::: "memory");
        asm volatile("s_waitcnt lgkmcnt(0)" ::: "memory");
        __builtin_amdgcn_s_barrier();
    }

    #pragma unroll 2
    for (int it = 0; it < 16; ++it) {
        const int cur = it & 1, nxt = cur ^ 1;
        if (it < 15) {
            const int k = (it + 1) * 64;
            #pragma unroll
            for (int i = 0; i < 6; ++i)
                async16(bsrc0 + k + i * 8192, &Blds[nxt][wid * 3072 + i * 512]);
        }
        f32x4 qa0, qa1;
        if (it < 14) {
            const int k2 = (it + 2) * 64;
            qa0 = *(const f32x4*)(asrc + k2);
            qa1 = *(const f32x4*)(asrc + k2 + 4);
        }
        #pragma unroll
        for (int kc = 0; kc < 2; ++kc) {
            const int q = kc * 64 + g * 16;
            short8 af[2], bf[3];
            #pragma unroll
            for (int mt = 0; mt < 2; ++mt) {
                const int rm = mt * 16 + c16;
                af[mt] = *(const short8*)&Alds[cur][rm * 64 + ((q ^ ((rm & 7) << 4)) >> 1)];
            }
            #pragma unroll
            for (int nt = 0; nt < 3; ++nt) {
                const int rb = wid * 48 + nt * 16 + c16;
                bf[nt] = *(const short8*)&Blds[cur][rb * 64 + ((q ^ ((rb & 7) << 4)) >> 1)];
            }
            #pragma unroll
            for (int mt = 0; mt < 2; ++mt)
                #pragma unroll
                for (int nt = 0; nt < 3; ++nt)
                    acc[mt][nt] = MFMA16(af[mt], bf[nt], acc[mt][nt]);
        }
        if (it < 15) {
            short8 p;
            ((unsigned int*)&p)[0] = cvtpk2(na0[0], na0[1]);
            ((unsigned int*)&p)[1] = cvtpk2(na0[2], na0[3]);
            ((unsigned int*)&p)[2] = cvtpk2(na1[0], na1[1]);
            ((unsigned int*)&p)[3] = cvtpk2(na1[2], na1[3]);
            if (it < 14) {
                asm volatile("s_waitcnt vmcnt(2)" ::: "memory");
            } else {
                asm volatile("s_waitcnt vmcnt(0)" ::: "memory");
            }
            *(short8*)&Alds[nxt][aoff] = p;
            asm volatile("s_waitcnt lgkmcnt(0)" ::: "memory");
            __builtin_amdgcn_s_barrier();
            na0 = qa0; na1 = qa1;
        }
    }

    const long bb = m0 >> 11;
    #pragma unroll
    for (int mt = 0; mt < 2; ++mt) {
        const long mrow = m0 + mt * 16 + g * 4;
        const long ss = mrow & 2047;
        #pragma unroll
        for (int nt = 0; nt < 3; ++nt) {
            const int n = wid * 48 + nt * 16 + c16;
            if (n < 64) {
                #pragma unroll
                for (int r = 0; r < 4; ++r)
                    Qb[(mrow + r) * 64 + n] = f2bf(acc[mt][nt][r]);
            } else if (n < 128) {
                #pragma unroll
                for (int r = 0; r < 4; ++r)
                    Kb[(mrow + r) * 64 + (n - 64)] = f2bf(acc[mt][nt][r]);
            } else {
                short4v pv = { (short)f2bf(acc[mt][nt][0]), (short)f2bf(acc[mt][nt][1]),
                               (short)f2bf(acc[mt][nt][2]), (short)f2bf(acc[mt][nt][3]) };
                *(short4v*)&Vt[((bb * 64) + (n - 128)) * 2048 + ss] = pv;
            }
        }
    }
}

// ---------------------------------------------------------------------------
// Kernel 2: causal attention. 32 q-rows PER WAVE (2 swapped-QK^T B-fragments
// share each K/V load -> 12 MFMA + 16 exp2 per 8KB step), in-register P,
// no max tracking (|s/8| < ~5). Block = 8 waves handles the causal pair of
// 32-row tiles {tA=pr, tB=63-pr} (nbA+nbB = 65 const); waves split between
// tiles proportionally, each kv-splitting its tile. Grid 256 = 1 block/CU,
// uniform cost, zero tail. Depth-1 ping-pong register prefetch of K/V.
// Merge in two 16-row passes (LDS 33KB).
// PV slot map: A slot k=8g+j  <->  kv = kv0 + (j>>2)*16 + 4g + (j&3).
// ---------------------------------------------------------------------------
__global__ __launch_bounds__(512) void attn_fwd(
    const unsigned short* __restrict__ Qb,
    const unsigned short* __restrict__ Kb,
    const unsigned short* __restrict__ Vt,
    float* __restrict__ out)
{
    __shared__ __align__(16) float Obuf[8 * 16 * 64];   // 32KB, reused 2 passes
    __shared__ float lbuf[8 * 32];                      // [wave][qlocal]

    const int tid  = threadIdx.x;
    const int lane = tid & 63;
    const int wid  = tid >> 6;          // 0..7
    const int c16  = lane & 15;
    const int g    = lane >> 4;
    const int bidx = blockIdx.x;
    const int b    = bidx & 7;          // batch -> XCD (L2 locality)
    const int pr   = bidx >> 3;         // 0..31
    const int tA   = pr;
    const int tB   = 63 - pr;

    const int nbA = tA + 1;             // kv32-blocks for 32-row tile t: t+1
    const int nbB = 64 - tA;            // nbA + nbB == 65
    int wA = (8 * nbA + 32) / 65;
    wA = max(1, min(7, wA));

    int q0, nb, nw, wi;
    if (wid < wA) { q0 = tA * 32; nb = nbA; nw = wA;     wi = wid; }
    else          { q0 = tB * 32; nb = nbB; nw = 8 - wA; wi = wid - wA; }
    const int cl  = (nb + nw - 1) / nw;
    const int blo = min(wi * cl, nb);
    const int bhi = min(blo + cl, nb);

    // Q fragments: 2 q-groups of 16 (B-operand cols = q0 + qg*16 + c16)
    short8 qf[2][2];
    #pragma unroll
    for (int qg = 0; qg < 2; ++qg) {
        const unsigned short* qrow = Qb + ((long)b * 2048 + q0 + qg * 16 + c16) * 64;
        qf[qg][0] = *(const short8*)(qrow + g * 8);
        qf[qg][1] = *(const short8*)(qrow + 32 + g * 8);
    }
    const unsigned short* Kbase = Kb + (long)b * 2048 * 64;
    const unsigned short* Vbase = Vt + (long)b * 64 * 2048;

    f32x4 acc[2][4];
    #pragma unroll
    for (int qg = 0; qg < 2; ++qg)
        #pragma unroll
        for (int vt = 0; vt < 4; ++vt) acc[qg][vt] = zero4();
    float lp[2] = {0.f, 0.f};

    const float SCL = 0.18033688f;   // log2(e)/8
    const int qgl[2] = { q0 + c16, q0 + 16 + c16 };

    short8 vfA[4], vfB[4];
    short8 kfA[2][2], kfB[2][2];

#define STEP_LOAD(KV0, VF, KF) do {                                            \
    const int _kv0 = (KV0);                                                    \
    _Pragma("unroll")                                                          \
    for (int vt = 0; vt < 4; ++vt) {                                           \
        const unsigned short* vrow =                                           \
            Vbase + (long)(vt * 16 + c16) * 2048 + _kv0 + 4 * g;               \
        ((short4v*)&VF[vt])[0] = *(const short4v*)vrow;                        \
        ((short4v*)&VF[vt])[1] = *(const short4v*)(vrow + 16);                 \
    }                                                                          \
    _Pragma("unroll")                                                          \
    for (int nt = 0; nt < 2; ++nt) {                                           \
        const unsigned short* krow =                                           \
            Kbase + (long)(_kv0 + nt * 16 + c16) * 64;                         \
        KF[nt][0] = *(const short8*)(krow + g * 8);                            \
        KF[nt][1] = *(const short8*)(krow + 32 + g * 8);                       \
    }                                                                          \
} while (0)

#define STEP_COMPUTE(KV0, VF, KF) do {                                         \
    const int _kv0 = (KV0);                                                    \
    f32x4 s[2][2];                                                             \
    _Pragma("unroll")                                                          \
    for (int nt = 0; nt < 2; ++nt)                                             \
        _Pragma("unroll")                                                      \
        for (int qg = 0; qg < 2; ++qg) {                                       \
            f32x4 z = zero4();                                                 \
            z = MFMA16(KF[nt][0], qf[qg][0], z);                               \
            z = MFMA16(KF[nt][1], qf[qg][1], z);                               \
            s[qg][nt] = z;                                                     \
        }                                                                      \
    _Pragma("unroll")                                                          \
    for (int qg = 0; qg < 2; ++qg) {                                           \
        short8 af;                                                             \
        _Pragma("unroll")                                                      \
        for (int nt = 0; nt < 2; ++nt) {                                       \
            float p[4];                                                        \
            _Pragma("unroll")                                                  \
            for (int r = 0; r < 4; ++r) {                                      \
                float v = exp2f(s[qg][nt][r] * SCL);                           \
                const int kvg = _kv0 + nt * 16 + g * 4 + r;                    \
                v = (kvg > qgl[qg]) ? 0.f : v;                                 \
                lp[qg] += v;                                                   \
                p[r] = v;                                                      \
            }                                                                  \
            ((unsigned int*)&af)[nt * 2]     = cvtpk2(p[0], p[1]);             \
            ((unsigned int*)&af)[nt * 2 + 1] = cvtpk2(p[2], p[3]);             \
        }                                                                      \
        _Pragma("unroll")                                                      \
        for (int vt = 0; vt < 4; ++vt)                                         \
            acc[qg][vt] = MFMA16(af, VF[vt], acc[qg][vt]);                     \
    }                                                                          \
} while (0)

    int blk = blo;
    if (blk < bhi) STEP_LOAD(blk * 32, vfA, kfA);
    while (blk < bhi) {
        if (blk + 1 < bhi) STEP_LOAD((blk + 1) * 32, vfB, kfB);
        STEP_COMPUTE(blk * 32, vfA, kfA);
        ++blk;
        if (blk >= bhi) break;
        if (blk + 1 < bhi) STEP_LOAD((blk + 1) * 32, vfA, kfA);
        STEP_COMPUTE(blk * 32, vfB, kfB);
        ++blk;
    }
#undef STEP_LOAD
#undef STEP_COMPUTE

    // l: reduce over the 4 g-groups holding each q
    #pragma unroll
    for (int qg = 0; qg < 2; ++qg) {
        lp[qg] += __shfl_xor(lp[qg], 16);
        lp[qg] += __shfl_xor(lp[qg], 32);
    }
    if (g == 0) {
        lbuf[wid * 32 + c16]      = lp[0];
        lbuf[wid * 32 + 16 + c16] = lp[1];
    }

    // merge in two passes (qg = 0,1), Obuf holds one 16-row group at a time
    #pragma unroll
    for (int qg = 0; qg < 2; ++qg) {
        __syncthreads();   // pass-0: covers lbuf; pass-1: covers prior reads
        #pragma unroll
        for (int vt = 0; vt < 4; ++vt)
            #pragma unroll
            for (int r = 0; r < 4; ++r)
                Obuf[(wid * 16 + g * 4 + r) * 64 + vt * 16 + c16] = acc[qg][vt][r];
        __syncthreads();

        const int tt  = tid >> 8;            // 0: tile A, 1: tile B
        const int row = (tid >> 4) & 15;
        const int c0  = (tid & 15) * 4;
        const int wlo = tt ? wA : 0;
        const int whi = tt ? 8  : wA;
        const int qrow = (tt ? tB : tA) * 32 + qg * 16 + row;

        float l = 0.f;
        for (int w = wlo; w < whi; ++w) l += lbuf[w * 32 + qg * 16 + row];
        const float inv = 1.0f / l;
        f32x4 o = zero4();
        for (int w = wlo; w < whi; ++w) {
            f32x4 t = *(const f32x4*)(Obuf + (w * 16 + row) * 64 + c0);
            #pragma unroll
            for (int j = 0; j < 4; ++j) o[j] += t[j];
        }
        #pragma unroll
        for (int j = 0; j < 4; ++j) o[j] *= inv;
        *(f32x4*)(out + ((long)b * 2048 + qrow) * 64 + c0) = o;
    }
}

extern "C" void kernel_launch(void* const* d_in, const int* in_sizes, int n_in,
                              void* d_out, int out_size, void* d_ws, size_t ws_size,
                              hipStream_t stream)
{
    const float* x  = (const float*)d_in[0];
    const float* wq = (const float*)d_in[1];
    const float* wk = (const float*)d_in[2];
    const float* wv = (const float*)d_in[3];

    unsigned short* Qb = (unsigned short*)d_ws;
    unsigned short* Kb = Qb + (size_t)16384 * 64;
    unsigned short* Vt = Kb + (size_t)16384 * 64;
    unsigned short* Wb = Vt + (size_t)8 * 64 * 2048;
    float* out = (float*)d_out;

    wconv<<<dim3(96), dim3(256), 0, stream>>>(wq, wk, wv, Wb);
    qkv_gemm<<<dim3(512), dim3(256), 0, stream>>>(x, Wb, Qb, Kb, Vt);
    attn_fwd<<<dim3(256), dim3(512), 0, stream>>>(Qb, Kb, Vt, out);
}

// Round 9
// 56.349 us; speedup vs baseline: 1.5547x; 1.0068x over previous
//
#include <hip/hip_runtime.h>
#include <hip/hip_bf16.h>

// B=8, S=2048, D_MODEL=1024, D_K=D_V=64, causal, fp32 in/out.
// ws: Qb bf16[16384][64] | Kb bf16[16384][64] | Vt bf16[8][64][2048] | Wb bf16[192][1024]

typedef __attribute__((ext_vector_type(4))) float f32x4;
typedef __attribute__((ext_vector_type(8))) short short8;
typedef __attribute__((ext_vector_type(4))) short short4v;

#define MFMA16(a, b, c) __builtin_amdgcn_mfma_f32_16x16x32_bf16((a), (b), (c), 0, 0, 0)

__device__ __forceinline__ unsigned short f2bf(float f) {
    unsigned int u = __float_as_uint(f);
    unsigned int r = (u + 0x7FFFu + ((u >> 16) & 1u)) >> 16;
    return (unsigned short)r;
}
// HW packed fp32->bf16 RNE (gfx950)
__device__ __forceinline__ unsigned int cvtpk2(float lo, float hi) {
    unsigned int r;
    asm("v_cvt_pk_bf16_f32 %0, %1, %2" : "=v"(r) : "v"(lo), "v"(hi));
    return r;
}
__device__ __forceinline__ f32x4 zero4() {
    f32x4 z = {0.f, 0.f, 0.f, 0.f};
    return z;
}
__device__ __forceinline__ void async16(const unsigned short* gsrc, unsigned short* ldst) {
    __builtin_amdgcn_global_load_lds(
        (const __attribute__((address_space(1))) unsigned int*)gsrc,
        (__attribute__((address_space(3))) unsigned int*)ldst, 16, 0, 0);
}

// ---------------------------------------------------------------------------
// Kernel 0: W_Q|W_K|W_V fp32[64][1024] -> Wb bf16[192][1024]
// ---------------------------------------------------------------------------
__global__ __launch_bounds__(256) void wconv(
    const float* __restrict__ wq, const float* __restrict__ wk,
    const float* __restrict__ wv, unsigned short* __restrict__ Wb)
{
    const int idx = (blockIdx.x * 256 + threadIdx.x) * 8;
    const int r = idx >> 10, c = idx & 1023;
    const float* src = (r < 64)  ? (wq + (long)r * 1024 + c)
                     : (r < 128) ? (wk + (long)(r - 64) * 1024 + c)
                     :             (wv + (long)(r - 128) * 1024 + c);
    f32x4 v0 = *(const f32x4*)src;
    f32x4 v1 = *(const f32x4*)(src + 4);
    short8 o;
    ((unsigned int*)&o)[0] = cvtpk2(v0[0], v0[1]);
    ((unsigned int*)&o)[1] = cvtpk2(v0[2], v0[3]);
    ((unsigned int*)&o)[2] = cvtpk2(v1[0], v1[1]);
    ((unsigned int*)&o)[3] = cvtpk2(v1[2], v1[3]);
    *(short8*)(Wb + idx) = o;
}

// ---------------------------------------------------------------------------
// Kernel 1: QKV GEMM. BM=32, BN=192, BK=64, dbuf LDS. BRANCHLESS main loop:
// prefetch indices clamped (redundant edge re-loads are free) so VMEM issue
// counts are path-independent and the counted vmcnt(2) pipeline holds.
// ---------------------------------------------------------------------------
__global__ __launch_bounds__(256, 2) void qkv_gemm(
    const float* __restrict__ x,
    const unsigned short* __restrict__ Wb,
    unsigned short* __restrict__ Qb,
    unsigned short* __restrict__ Kb,
    unsigned short* __restrict__ Vt)
{
    __shared__ __align__(16) unsigned short Blds[2][192 * 64];
    __shared__ __align__(16) unsigned short Alds[2][32 * 64];

    const int tid  = threadIdx.x;
    const int lane = tid & 63;
    const int wid  = tid >> 6;
    const int c16  = lane & 15;
    const int g    = lane >> 4;
    const long m0  = (long)blockIdx.x * 32;

    const int o0    = wid * 6144 + lane * 16;
    const int brow0 = o0 >> 7;
    const int boff0 = o0 & 127;
    const unsigned short* bsrc0 =
        Wb + (long)brow0 * 1024 + ((boff0 ^ ((brow0 & 7) << 4)) >> 1);

    const int ar  = tid >> 3, acq = tid & 7;
    const float* asrc = x + (m0 + ar) * 1024 + acq * 8;
    const int aoff = ar * 64 + (((acq * 16) ^ ((ar & 7) << 4)) >> 1);

    f32x4 acc[2][3];
    #pragma unroll
    for (int i = 0; i < 2; ++i)
        #pragma unroll
        for (int j = 0; j < 3; ++j) acc[i][j] = zero4();

    // ---- prologue: A(0)->LDS0 + B(0) asyncs + A(1)->regs ----
    f32x4 na0, na1;
    {
        f32x4 pa0 = *(const f32x4*)asrc;
        f32x4 pa1 = *(const f32x4*)(asrc + 4);
        #pragma unroll
        for (int i = 0; i < 6; ++i)
            async16(bsrc0 + i * 8192, &Blds[0][wid * 3072 + i * 512]);
        na0 = *(const f32x4*)(asrc + 64);
        na1 = *(const f32x4*)(asrc + 68);
        short8 p;
        ((unsigned int*)&p)[0] = cvtpk2(pa0[0], pa0[1]);
        ((unsigned int*)&p)[1] = cvtpk2(pa0[2], pa0[3]);
        ((unsigned int*)&p)[2] = cvtpk2(pa1[0], pa1[1]);
        ((unsigned int*)&p)[3] = cvtpk2(pa1[2], pa1[3]);
        *(short8*)&Alds[0][aoff] = p;
        asm volatile("s_waitcnt vmcnt(2)" ::: "memory");   // B(0) landed; A(1) flying
        asm volatile("s_waitcnt lgkmcnt(0)" ::: "memory");
        __builtin_amdgcn_s_barrier();
    }

    #pragma unroll 2
    for (int it = 0; it < 16; ++it) {
        const int cur = it & 1, nxt = cur ^ 1;
        // branchless prefetch (clamped at the edge: redundant, harmless)
        const int kb = min(it + 1, 15) * 64;
        #pragma unroll
        for (int i = 0; i < 6; ++i)
            async16(bsrc0 + kb + i * 8192, &Blds[nxt][wid * 3072 + i * 512]);
        const int ka = min(it + 2, 15) * 64;
        f32x4 qa0 = *(const f32x4*)(asrc + ka);
        f32x4 qa1 = *(const f32x4*)(asrc + ka + 4);
        // ---- compute on cur ----
        #pragma unroll
        for (int kc = 0; kc < 2; ++kc) {
            const int q = kc * 64 + g * 16;
            short8 af[2], bf[3];
            #pragma unroll
            for (int mt = 0; mt < 2; ++mt) {
                const int rm = mt * 16 + c16;
                af[mt] = *(const short8*)&Alds[cur][rm * 64 + ((q ^ ((rm & 7) << 4)) >> 1)];
            }
            #pragma unroll
            for (int nt = 0; nt < 3; ++nt) {
                const int rb = wid * 48 + nt * 16 + c16;
                bf[nt] = *(const short8*)&Blds[cur][rb * 64 + ((q ^ ((rb & 7) << 4)) >> 1)];
            }
            __builtin_amdgcn_s_setprio(1);
            #pragma unroll
            for (int mt = 0; mt < 2; ++mt)
                #pragma unroll
                for (int nt = 0; nt < 3; ++nt)
                    acc[mt][nt] = MFMA16(af[mt], bf[nt], acc[mt][nt]);
            __builtin_amdgcn_s_setprio(0);
        }
        // ---- stage A(it+1) regs -> LDS(nxt); drain only B asyncs ----
        {
            short8 p;
            ((unsigned int*)&p)[0] = cvtpk2(na0[0], na0[1]);
            ((unsigned int*)&p)[1] = cvtpk2(na0[2], na0[3]);
            ((unsigned int*)&p)[2] = cvtpk2(na1[0], na1[1]);
            ((unsigned int*)&p)[3] = cvtpk2(na1[2], na1[3]);
            asm volatile("s_waitcnt vmcnt(2)" ::: "memory");   // 6 B done; 2 A flying
            *(short8*)&Alds[nxt][aoff] = p;
            asm volatile("s_waitcnt lgkmcnt(0)" ::: "memory");
            __builtin_amdgcn_s_barrier();
            na0 = qa0; na1 = qa1;
        }
    }

    // ---- epilogue: D layout col=c16, row=g*4+r ----
    const long bb = m0 >> 11;
    #pragma unroll
    for (int mt = 0; mt < 2; ++mt) {
        const long mrow = m0 + mt * 16 + g * 4;
        const long ss = mrow & 2047;
        #pragma unroll
        for (int nt = 0; nt < 3; ++nt) {
            const int n = wid * 48 + nt * 16 + c16;
            if (n < 64) {
                #pragma unroll
                for (int r = 0; r < 4; ++r)
                    Qb[(mrow + r) * 64 + n] = f2bf(acc[mt][nt][r]);
            } else if (n < 128) {
                #pragma unroll
                for (int r = 0; r < 4; ++r)
                    Kb[(mrow + r) * 64 + (n - 64)] = f2bf(acc[mt][nt][r]);
            } else {
                short4v pv = { (short)f2bf(acc[mt][nt][0]), (short)f2bf(acc[mt][nt][1]),
                               (short)f2bf(acc[mt][nt][2]), (short)f2bf(acc[mt][nt][3]) };
                *(short4v*)&Vt[((bb * 64) + (n - 128)) * 2048 + ss] = pv;
            }
        }
    }
}

// ---------------------------------------------------------------------------
// Kernel 2: causal attention. 32 q-rows per wave, swapped-QK^T, in-register
// P, no max tracking. Block = 8 waves on the causal pair {tA=pr, tB=63-pr}
// (nbA+nbB = 65), waves split between tiles prop. to cost. BRANCHLESS
// depth-1 ping-pong prefetch (clamped indices) so the compiler emits counted
// vmcnt instead of a full drain. s_setprio around MFMA clusters (T5).
// PV slot map: A slot k=8g+j  <->  kv = kv0 + (j>>2)*16 + 4g + (j&3).
// ---------------------------------------------------------------------------
__global__ __launch_bounds__(512) void attn_fwd(
    const unsigned short* __restrict__ Qb,
    const unsigned short* __restrict__ Kb,
    const unsigned short* __restrict__ Vt,
    float* __restrict__ out)
{
    __shared__ __align__(16) float Obuf[8 * 16 * 64];   // 32KB, reused 2 passes
    __shared__ float lbuf[8 * 32];                      // [wave][qlocal]

    const int tid  = threadIdx.x;
    const int lane = tid & 63;
    const int wid  = tid >> 6;          // 0..7
    const int c16  = lane & 15;
    const int g    = lane >> 4;
    const int bidx = blockIdx.x;
    const int b    = bidx & 7;          // batch -> XCD (L2 locality)
    const int pr   = bidx >> 3;         // 0..31
    const int tA   = pr;
    const int tB   = 63 - pr;

    const int nbA = tA + 1;
    const int nbB = 64 - tA;            // nbA + nbB == 65
    int wA = (8 * nbA + 32) / 65;
    wA = max(1, min(7, wA));

    int q0, nb, nw, wi;
    if (wid < wA) { q0 = tA * 32; nb = nbA; nw = wA;     wi = wid; }
    else          { q0 = tB * 32; nb = nbB; nw = 8 - wA; wi = wid - wA; }
    const int cl  = (nb + nw - 1) / nw;
    const int blo = min(wi * cl, nb);
    const int bhi = min(blo + cl, nb);

    short8 qf[2][2];
    #pragma unroll
    for (int qg = 0; qg < 2; ++qg) {
        const unsigned short* qrow = Qb + ((long)b * 2048 + q0 + qg * 16 + c16) * 64;
        qf[qg][0] = *(const short8*)(qrow + g * 8);
        qf[qg][1] = *(const short8*)(qrow + 32 + g * 8);
    }
    const unsigned short* Kbase = Kb + (long)b * 2048 * 64;
    const unsigned short* Vbase = Vt + (long)b * 64 * 2048;

    f32x4 acc[2][4];
    #pragma unroll
    for (int qg = 0; qg < 2; ++qg)
        #pragma unroll
        for (int vt = 0; vt < 4; ++vt) acc[qg][vt] = zero4();
    f32x4 lp4[2];
    lp4[0] = zero4(); lp4[1] = zero4();

    const float SCL = 0.18033688f;   // log2(e)/8
    const int qgl[2] = { q0 + c16, q0 + 16 + c16 };

    short8 vfA[4], vfB[4];
    short8 kfA[2][2], kfB[2][2];

#define STEP_LOAD(KV0, VF, KF) do {                                            \
    const int _kv0 = (KV0);                                                    \
    _Pragma("unroll")                                                          \
    for (int vt = 0; vt < 4; ++vt) {                                           \
        const unsigned short* vrow =                                           \
            Vbase + (long)(vt * 16 + c16) * 2048 + _kv0 + 4 * g;               \
        ((short4v*)&VF[vt])[0] = *(const short4v*)vrow;                        \
        ((short4v*)&VF[vt])[1] = *(const short4v*)(vrow + 16);                 \
    }                                                                          \
    _Pragma("unroll")                                                          \
    for (int nt = 0; nt < 2; ++nt) {                                           \
        const unsigned short* krow =                                           \
            Kbase + (long)(_kv0 + nt * 16 + c16) * 64;                         \
        KF[nt][0] = *(const short8*)(krow + g * 8);                            \
        KF[nt][1] = *(const short8*)(krow + 32 + g * 8);                       \
    }                                                                          \
} while (0)

#define STEP_COMPUTE(KV0, VF, KF) do {                                         \
    const int _kv0 = (KV0);                                                    \
    f32x4 s[2][2];                                                             \
    __builtin_amdgcn_s_setprio(1);                                             \
    _Pragma("unroll")                                                          \
    for (int nt = 0; nt < 2; ++nt)                                             \
        _Pragma("unroll")                                                      \
        for (int qg = 0; qg < 2; ++qg) {                                       \
            f32x4 z = zero4();                                                 \
            z = MFMA16(KF[nt][0], qf[qg][0], z);                               \
            z = MFMA16(KF[nt][1], qf[qg][1], z);                               \
            s[qg][nt] = z;                                                     \
        }                                                                      \
    __builtin_amdgcn_s_setprio(0);                                             \
    short8 af[2];                                                              \
    _Pragma("unroll")                                                          \
    for (int qg = 0; qg < 2; ++qg) {                                           \
        _Pragma("unroll")                                                      \
        for (int nt = 0; nt < 2; ++nt) {                                       \
            float p[4];                                                        \
            _Pragma("unroll")                                                  \
            for (int r = 0; r < 4; ++r) {                                      \
                float v = exp2f(s[qg][nt][r] * SCL);                           \
                const int kvg = _kv0 + nt * 16 + g * 4 + r;                    \
                v = (kvg > qgl[qg]) ? 0.f : v;                                 \
                lp4[qg][r] += v;                                               \
                p[r] = v;                                                      \
            }                                                                  \
            ((unsigned int*)&af[qg])[nt * 2]     = cvtpk2(p[0], p[1]);         \
            ((unsigned int*)&af[qg])[nt * 2 + 1] = cvtpk2(p[2], p[3]);         \
        }                                                                      \
    }                                                                          \
    __builtin_amdgcn_s_setprio(1);                                             \
    _Pragma("unroll")                                                          \
    for (int qg = 0; qg < 2; ++qg)                                             \
        _Pragma("unroll")                                                      \
        for (int vt = 0; vt < 4; ++vt)                                         \
            acc[qg][vt] = MFMA16(af[qg], VF[vt], acc[qg][vt]);                 \
    __builtin_amdgcn_s_setprio(0);                                             \
} while (0)

    const int steps = bhi - blo;
    int blk = blo;
    if (steps > 0) {
        STEP_LOAD(blk * 32, vfA, kfA);
        int i = 0;
        for (; i + 2 <= steps; i += 2) {
            STEP_LOAD((blk + 1) * 32, vfB, kfB);      // unconditional: blk+1 < bhi
            STEP_COMPUTE(blk * 32, vfA, kfA);
            const int nn = min(blk + 2, bhi - 1);     // clamped: branchless
            STEP_LOAD(nn * 32, vfA, kfA);
            STEP_COMPUTE((blk + 1) * 32, vfB, kfB);
            blk += 2;
        }
        if (i < steps)
            STEP_COMPUTE(blk * 32, vfA, kfA);         // odd tail, already loaded
    }
#undef STEP_LOAD
#undef STEP_COMPUTE

    float lp[2];
    #pragma unroll
    for (int qg = 0; qg < 2; ++qg) {
        lp[qg] = (lp4[qg][0] + lp4[qg][1]) + (lp4[qg][2] + lp4[qg][3]);
        lp[qg] += __shfl_xor(lp[qg], 16);
        lp[qg] += __shfl_xor(lp[qg], 32);
    }
    if (g == 0) {
        lbuf[wid * 32 + c16]      = lp[0];
        lbuf[wid * 32 + 16 + c16] = lp[1];
    }

    // merge in two passes (qg = 0,1), Obuf holds one 16-row group at a time
    #pragma unroll
    for (int qg = 0; qg < 2; ++qg) {
        __syncthreads();
        #pragma unroll
        for (int vt = 0; vt < 4; ++vt)
            #pragma unroll
            for (int r = 0; r < 4; ++r)
                Obuf[(wid * 16 + g * 4 + r) * 64 + vt * 16 + c16] = acc[qg][vt][r];
        __syncthreads();

        const int tt  = tid >> 8;            // 0: tile A, 1: tile B
        const int row = (tid >> 4) & 15;
        const int c0  = (tid & 15) * 4;
        const int wlo = tt ? wA : 0;
        const int whi = tt ? 8  : wA;
        const int qrow = (tt ? tB : tA) * 32 + qg * 16 + row;

        float l = 0.f;
        for (int w = wlo; w < whi; ++w) l += lbuf[w * 32 + qg * 16 + row];
        const float inv = 1.0f / l;
        f32x4 o = zero4();
        for (int w = wlo; w < whi; ++w) {
            f32x4 t = *(const f32x4*)(Obuf + (w * 16 + row) * 64 + c0);
            #pragma unroll
            for (int j = 0; j < 4; ++j) o[j] += t[j];
        }
        #pragma unroll
        for (int j = 0; j < 4; ++j) o[j] *= inv;
        *(f32x4*)(out + ((long)b * 2048 + qrow) * 64 + c0) = o;
    }
}

extern "C" void kernel_launch(void* const* d_in, const int* in_sizes, int n_in,
                              void* d_out, int out_size, void* d_ws, size_t ws_size,
                              hipStream_t stream)
{
    const float* x  = (const float*)d_in[0];
    const float* wq = (const float*)d_in[1];
    const float* wk = (const float*)d_in[2];
    const float* wv = (const float*)d_in[3];

    unsigned short* Qb = (unsigned short*)d_ws;
    unsigned short* Kb = Qb + (size_t)16384 * 64;
    unsigned short* Vt = Kb + (size_t)16384 * 64;
    unsigned short* Wb = Vt + (size_t)8 * 64 * 2048;
    float* out = (float*)d_out;

    wconv<<<dim3(96), dim3(256), 0, stream>>>(wq, wk, wv, Wb);
    qkv_gemm<<<dim3(512), dim3(256), 0, stream>>>(x, Wb, Qb, Kb, Vt);
    attn_fwd<<<dim3(256), dim3(512), 0, stream>>>(Qb, Kb, Vt, out);
}